// Round 11
// baseline (300.602 us; speedup 1.0000x reference)
//
#include <hip/hip_runtime.h>

#define U_ROWS 20000
#define I_COLS 10000
#define LDI    10001
#define B_N    4096
#define SC     625        // 32-row groups (20000/32)
#define ABP    10240      // Abit words per s-group (col-padded, zero beyond 9999)
#define NPAN_C 79         // c-gemm i-panels of 128
#define NC_C   8          // c-gemm K-split
#define NP_U   8          // u-gemm K-split
#define KKT    316        // u-gemm total 32-wide k-steps (covers 10112 >= 10000)
#define SU_P   316        // packed B k-steps for u-gemm
#define SQ     5          // bitize col-tiles of 2048

typedef __attribute__((ext_vector_type(8))) __bf16 bf16x8;
typedef __attribute__((ext_vector_type(4))) float f32x4;

__device__ __forceinline__ unsigned short f2bf(float f) {
    unsigned int u = __float_as_uint(f);
    return (unsigned short)((u + 0x7FFFu + ((u >> 16) & 1u)) >> 16);  // RTN-even
}

// expand 8 bits (b0..b7) -> bf16x8 {0,1.0}; dword q = {bit 2q (lo), bit 2q+1 (hi)}
__device__ __forceinline__ bf16x8 expand8(unsigned int byte) {
    union { unsigned int i[4]; bf16x8 v; } af;
#pragma unroll
    for (int q = 0; q < 4; ++q) {
        unsigned int lo = (byte & (1u << (2 * q)))     ? 0x00003F80u : 0u;
        unsigned int hi = (byte & (1u << (2 * q + 1))) ? 0x3F800000u : 0u;
        af.i[q] = lo | hi;
    }
    return af.v;
}

// Pass 1: A -> column bitmask Abit[s][c] (bit r = row s*32+r), plus weight prep.
//  blocks [0, SC*SQ): tile (s = bid/SQ, q = bid%SQ): 32 rows x 2048 cols.
//  WIDE+ALIGNED loads: row r has flat-base phase p = r&3 (LDI = 10001 == 1 mod 4);
//  loads issue at g0 = row_start + W0 - p (16B-aligned, 2x f32x4/thread = 1KB-aligned
//  wave spans). In-register realign: src[j] = j+p<8 ? v[j+p] : lane+1's v[j+p-8]
//  (via shfl; lane 63 patched from one predicated extra x4 at g0+512).
//  blocks [SC*SQ, +): Pu/Pi MFMA-order packs + MLP weight transposes.
__global__ __launch_bounds__(256) void k_bitize(
    const float* __restrict__ A, unsigned int* __restrict__ Abit,
    const float* __restrict__ Wu, const float* __restrict__ Wi,
    unsigned short* __restrict__ Pu, unsigned short* __restrict__ Pi,
    const float* __restrict__ W1, const float* __restrict__ W2, const float* __restrict__ W3,
    float* __restrict__ Wt1, float* __restrict__ Wt2, float* __restrict__ Wt3)
{
    const int t = threadIdx.x;
    if ((int)blockIdx.x < SC * SQ) {
        const int s = blockIdx.x / SQ, q = blockIdx.x % SQ;
        const int lane = t & 63, w = t >> 6;
        const int W0 = q * 2048 + (w << 9);          // wave's logical col base
        const size_t row0 = (size_t)s * 32 * LDI;

        unsigned int acc[8];
#pragma unroll
        for (int j = 0; j < 8; ++j) acc[j] = 0u;

#pragma unroll
        for (int r4 = 0; r4 < 8; ++r4) {
#pragma unroll
            for (int p = 0; p < 4; ++p) {            // p == phase of row r (compile-time)
                const int r = r4 * 4 + p;
                const float* g0 = A + row0 + (size_t)r * LDI + W0 - p;
                f32x4 v0 = *(const f32x4*)(g0 + 8 * lane);
                f32x4 v1 = *(const f32x4*)(g0 + 8 * lane + 4);
                float vv[8] = {v0[0], v0[1], v0[2], v0[3], v1[0], v1[1], v1[2], v1[3]};
                float fx[3] = {0.f, 0.f, 0.f};
                if (p > 0) {
                    f32x4 ex = (f32x4)(0.0f);
                    if (lane == 63) ex = *(const f32x4*)(g0 + 512);
#pragma unroll
                    for (int j = 0; j < p; ++j) {
                        float nb = __shfl(vv[j], lane + 1);       // lane 63 wraps (fixed below)
                        fx[j] = (lane == 63) ? ex[j] : nb;
                    }
                }
#pragma unroll
                for (int j = 0; j < 8; ++j) {
                    float sv = (j + p < 8) ? vv[j + p] : fx[j + p - 8];
                    unsigned int bit = (__float_as_uint(sv) >> 23) & 1u;  // 1.0->1, 0.0->0
                    acc[j] |= bit << r;
                }
            }
        }

        const int c0 = W0 + 8 * lane;
#pragma unroll
        for (int j = 0; j < 8; ++j)
            if (c0 + j >= I_COLS) acc[j] = 0u;       // excluded / padding cols
        unsigned int* ob = Abit + (size_t)s * ABP + c0;
        uint4 o0, o1;
        o0.x = acc[0]; o0.y = acc[1]; o0.z = acc[2]; o0.w = acc[3];
        o1.x = acc[4]; o1.y = acc[5]; o1.z = acc[6]; o1.w = acc[7];
        *(uint4*)(ob)     = o0;
        *(uint4*)(ob + 4) = o1;
        return;
    }

    // ---- fused prep ----
    const int NU = SU_P * 2048, NC2 = SC * 2048;
    int idx = ((int)blockIdx.x - SC * SQ) * 256 + t;
    if (idx < NU + NC2) {
        const float* W = (idx < NU) ? Wu : Wi;
        unsigned short* out = (idx < NU) ? Pu : Pi;
        int n_k = (idx < NU) ? I_COLS : U_ROWS;
        int li = (idx < NU) ? idx : idx - NU;
        int j  = li & 7;
        int l  = (li >> 3) & 63;
        int nb = (li >> 9) & 3;
        int s  = li >> 11;
        int n  = nb * 16 + (l & 15);
        int k  = s * 32 + ((l >> 4) << 3) + j;
        float v = (k < n_k) ? W[(size_t)n * n_k + k] : 0.0f;
        out[li] = f2bf(v);
        return;
    }
    int r2 = idx - (NU + NC2);
    if (r2 < 64 * 128) { int r = r2 / 128, c = r2 % 128; Wt1[c * 64 + r] = W1[r2]; return; }
    r2 -= 64 * 128;
    if (r2 < 32 * 64)  { int r = r2 / 64,  c = r2 % 64;  Wt2[c * 32 + r] = W2[r2]; return; }
    r2 -= 32 * 64;
    if (r2 < 16 * 32)  { int r = r2 / 32,  c = r2 % 32;  Wt3[c * 16 + r] = W3[r2]; return; }
}

// Pass 2: both GEMMs from the bitmask. No LDS, no barriers.
//  blocks [0, NPAN_C*NC_C):  Cpart[p][i][n] = sum_u A[u,i]*Wi[n,u]
//  blocks [+, +64*NP_U):     Upart[p][r][n] = sum_k A[u_r,k]*Wu[n,k]
__global__ __launch_bounds__(256) void k_gemm2(
    const unsigned int* __restrict__ Abit, const int* __restrict__ uidx,
    const unsigned short* __restrict__ Bpu, const unsigned short* __restrict__ Bpc,
    float* __restrict__ Upart, float* __restrict__ Cpart)
{
    const int t = threadIdx.x, lane = t & 63, w = t >> 6;
    const int rl = lane & 15, g = lane >> 4;
    const int CB = NPAN_C * NC_C;

    if ((int)blockIdx.x < CB) {
        // ---------------- c-gemm ----------------
        const int p = blockIdx.x % NC_C, mb = blockIdx.x / NC_C;
        const int i0 = mb * 128;
        const int spc = (SC + NC_C - 1) / NC_C;
        const int s0 = p * spc;
        const int s1 = (SC < s0 + spc) ? SC : (s0 + spc);
        const int widx = i0 + w * 32 + rl;
        const int gsh = g * 8;

        f32x4 acc[2][4];
#pragma unroll
        for (int mt = 0; mt < 2; ++mt)
#pragma unroll
            for (int nb = 0; nb < 4; ++nb) acc[mt][nb] = (f32x4)(0.0f);

        for (int s = s0; s < s1; ++s) {
            const unsigned int* ws = Abit + (size_t)s * ABP + widx;
            unsigned int Wd0 = ws[0];
            unsigned int Wd1 = ws[16];
            bf16x8 bv[4];
#pragma unroll
            for (int nb = 0; nb < 4; ++nb)
                bv[nb] = *(const bf16x8*)(Bpc + ((size_t)(s * 4 + nb) * 64 + lane) * 8);
            bf16x8 a0 = expand8((Wd0 >> gsh) & 0xFFu);
            bf16x8 a1 = expand8((Wd1 >> gsh) & 0xFFu);
#pragma unroll
            for (int nb = 0; nb < 4; ++nb)
                acc[0][nb] = __builtin_amdgcn_mfma_f32_16x16x32_bf16(a0, bv[nb], acc[0][nb], 0, 0, 0);
#pragma unroll
            for (int nb = 0; nb < 4; ++nb)
                acc[1][nb] = __builtin_amdgcn_mfma_f32_16x16x32_bf16(a1, bv[nb], acc[1][nb], 0, 0, 0);
        }

        float* outp = Cpart + (size_t)p * I_COLS * 64;
#pragma unroll
        for (int mt = 0; mt < 2; ++mt)
#pragma unroll
            for (int nb = 0; nb < 4; ++nb)
#pragma unroll
                for (int reg = 0; reg < 4; ++reg) {
                    int i = i0 + w * 32 + mt * 16 + g * 4 + reg;
                    if (i < I_COLS) outp[(size_t)i * 64 + nb * 16 + rl] = acc[mt][nb][reg];
                }
    } else {
        // ---------------- u-gemm ----------------
        const int bid = blockIdx.x - CB;
        const int p = bid % NP_U, mb = bid / NP_U;
        const int r0 = mb * 64;
        const int spk = (KKT + NP_U - 1) / NP_U;          // 40
        const int kk0 = p * spk;
        const int kk1 = (KKT < kk0 + spk) ? KKT : (kk0 + spk);

        const int ur = uidx[r0 + w * 16 + rl];
        const unsigned int* wrow = Abit + (size_t)(ur >> 5) * ABP;
        const int bp = ur & 31;

        f32x4 acc[4];
#pragma unroll
        for (int nb = 0; nb < 4; ++nb) acc[nb] = (f32x4)(0.0f);

        uint4 pa0 = *(const uint4*)(wrow + kk0 * 32 + g * 8);
        uint4 pa1 = *(const uint4*)(wrow + kk0 * 32 + g * 8 + 4);
        for (int kk = kk0; kk < kk1; ++kk) {
            uint4 a0 = pa0, a1 = pa1;
            if (kk + 1 < kk1) {
                pa0 = *(const uint4*)(wrow + (kk + 1) * 32 + g * 8);
                pa1 = *(const uint4*)(wrow + (kk + 1) * 32 + g * 8 + 4);
            }
            unsigned int wd[8] = {a0.x, a0.y, a0.z, a0.w, a1.x, a1.y, a1.z, a1.w};
            union { unsigned int i[4]; bf16x8 v; } af;
#pragma unroll
            for (int q = 0; q < 4; ++q) {
                unsigned int lo = ((wd[2 * q]     >> bp) & 1u) ? 0x00003F80u : 0u;
                unsigned int hi = ((wd[2 * q + 1] >> bp) & 1u) ? 0x3F800000u : 0u;
                af.i[q] = lo | hi;
            }
            bf16x8 bv[4];
#pragma unroll
            for (int nb = 0; nb < 4; ++nb)
                bv[nb] = *(const bf16x8*)(Bpu + ((size_t)(kk * 4 + nb) * 64 + lane) * 8);
#pragma unroll
            for (int nb = 0; nb < 4; ++nb)
                acc[nb] = __builtin_amdgcn_mfma_f32_16x16x32_bf16(af.v, bv[nb], acc[nb], 0, 0, 0);
        }

        float* outp = Upart + (size_t)p * B_N * 64;
#pragma unroll
        for (int nb = 0; nb < 4; ++nb)
#pragma unroll
            for (int reg = 0; reg < 4; ++reg) {
                int r = r0 + w * 16 + g * 4 + reg;
                outp[(size_t)r * 64 + nb * 16 + rl] = acc[nb][reg];
            }
    }
}

__device__ __forceinline__ float redsum64(float x) {
    x += __shfl_xor(x, 1);  x += __shfl_xor(x, 2);  x += __shfl_xor(x, 4);
    x += __shfl_xor(x, 8);  x += __shfl_xor(x, 16); x += __shfl_xor(x, 32);
    return x;
}
__device__ __forceinline__ float redsum32(float x) {
    x += __shfl_xor(x, 1); x += __shfl_xor(x, 2); x += __shfl_xor(x, 4);
    x += __shfl_xor(x, 8); x += __shfl_xor(x, 16);
    return x;
}
__device__ __forceinline__ float redsum16(float x) {
    x += __shfl_xor(x, 1); x += __shfl_xor(x, 2); x += __shfl_xor(x, 4);
    x += __shfl_xor(x, 8);
    return x;
}

// one wave per batch row: reduce partials, mask corrections, full MLP
__global__ __launch_bounds__(256) void k_epi(
    const float* __restrict__ A, const int* __restrict__ uidx, const int* __restrict__ iidx,
    const float* __restrict__ Upart, const float* __restrict__ Cpart,
    const float* __restrict__ Wu, const float* __restrict__ Wi,
    const float* __restrict__ Wt1, const float* __restrict__ b1, const float* __restrict__ g1, const float* __restrict__ be1,
    const float* __restrict__ Wt2, const float* __restrict__ b2, const float* __restrict__ g2, const float* __restrict__ be2,
    const float* __restrict__ Wt3, const float* __restrict__ b3, const float* __restrict__ g3, const float* __restrict__ be3,
    const float* __restrict__ Wp, const float* __restrict__ bp,
    float* __restrict__ out)
{
    const int t = threadIdx.x, lane = t & 63, w = t >> 6;
    const int r = blockIdx.x * 4 + w;
    const int u = uidx[r], it = iidx[r];
    const float a_ui = A[(size_t)u * LDI + it];

    float ue = 0.f, ie = 0.f;
    for (int p0 = 0; p0 < NP_U; ++p0) ue += Upart[((size_t)p0 * B_N + r) * 64 + lane];
    for (int p0 = 0; p0 < NC_C; ++p0) ie += Cpart[((size_t)p0 * I_COLS + it) * 64 + lane];
    ue -= a_ui * Wu[(size_t)lane * I_COLS + it];
    ie -= a_ui * Wi[(size_t)lane * U_ROWS + u];

    // layer 1: 128 -> 64, LN, ReLU
    float h = b1[lane];
    for (int c = 0; c < 64; ++c) h += __shfl(ue, c) * Wt1[c * 64 + lane];
    for (int c = 0; c < 64; ++c) h += __shfl(ie, c) * Wt1[(64 + c) * 64 + lane];
    {
        float m = redsum64(h) * (1.0f / 64.0f);
        float d = h - m;
        float v = redsum64(d * d) * (1.0f / 64.0f);
        h = d * rsqrtf(v + 1e-5f) * g1[lane] + be1[lane];
        h = fmaxf(h, 0.0f);
    }
    // layer 2: 64 -> 32
    const int l2 = lane & 31;
    float h2 = b2[l2];
    for (int c = 0; c < 64; ++c) h2 += __shfl(h, c) * Wt2[c * 32 + l2];
    {
        float m = redsum32(h2) * (1.0f / 32.0f);
        float d = h2 - m;
        float v = redsum32(d * d) * (1.0f / 32.0f);
        h2 = d * rsqrtf(v + 1e-5f) * g2[l2] + be2[l2];
        h2 = fmaxf(h2, 0.0f);
    }
    // layer 3: 32 -> 16
    const int l3 = lane & 15;
    float h3 = b3[l3];
    for (int c = 0; c < 32; ++c) h3 += __shfl(h2, c) * Wt3[c * 16 + l3];
    {
        float m = redsum16(h3) * (1.0f / 16.0f);
        float d = h3 - m;
        float v = redsum16(d * d) * (1.0f / 16.0f);
        h3 = d * rsqrtf(v + 1e-5f) * g3[l3] + be3[l3];
        h3 = fmaxf(h3, 0.0f);
    }
    float tt = h3 * Wp[l3];
    tt = redsum16(tt);
    if (lane == 0) out[r] = tt + bp[0];
}

extern "C" void kernel_launch(void* const* d_in, const int* in_sizes, int n_in,
                              void* d_out, int out_size, void* d_ws, size_t ws_size,
                              hipStream_t stream)
{
    const float* A    = (const float*)d_in[0];
    const int*   uidx = (const int*)d_in[1];
    const int*   iidx = (const int*)d_in[2];
    const float* W_u  = (const float*)d_in[3];
    const float* W_i  = (const float*)d_in[4];
    const float* W1   = (const float*)d_in[5];
    const float* b1   = (const float*)d_in[6];
    const float* g1   = (const float*)d_in[7];
    const float* be1  = (const float*)d_in[8];
    const float* W2   = (const float*)d_in[9];
    const float* b2   = (const float*)d_in[10];
    const float* g2   = (const float*)d_in[11];
    const float* be2  = (const float*)d_in[12];
    const float* W3   = (const float*)d_in[13];
    const float* b3   = (const float*)d_in[14];
    const float* g3   = (const float*)d_in[15];
    const float* be3  = (const float*)d_in[16];
    const float* Wp   = (const float*)d_in[17];
    const float* bp   = (const float*)d_in[18];
    float* out = (float*)d_out;

    // workspace carving
    unsigned int*  Abit = (unsigned int*)d_ws;                    // SC*ABP words = 25.6 MB
    unsigned short* Wtu_p = (unsigned short*)(Abit + (size_t)SC * ABP);
    unsigned short* Wti_p = Wtu_p + (size_t)SU_P * 2048;
    float* Wt1 = (float*)(Wti_p + (size_t)SC * 2048);
    float* Wt2 = Wt1 + 128 * 64;
    float* Wt3 = Wt2 + 64 * 32;
    float* Upart = Wt3 + 32 * 16;                                 // NP_U*B_N*64
    float* Cpart = Upart + (size_t)NP_U * B_N * 64;               // NC_C*I_COLS*64

    int prep_tot = (SU_P + SC) * 2048 + 64 * 128 + 32 * 64 + 16 * 32;
    int grid1 = SC * SQ + (prep_tot + 255) / 256;

    hipLaunchKernelGGL(k_bitize, dim3(grid1), dim3(256), 0, stream,
                       A, Abit, W_u, W_i, Wtu_p, Wti_p,
                       W1, W2, W3, Wt1, Wt2, Wt3);

    hipLaunchKernelGGL(k_gemm2, dim3(NPAN_C * NC_C + 64 * NP_U), dim3(256), 0, stream,
                       Abit, uidx, Wtu_p, Wti_p, Upart, Cpart);

    hipLaunchKernelGGL(k_epi, dim3(B_N / 4), dim3(256), 0, stream,
                       A, uidx, iidx, Upart, Cpart, W_u, W_i,
                       Wt1, b1, g1, be1, Wt2, b2, g2, be2,
                       Wt3, b3, g3, be3, Wp, bp, out);
}

// Round 12
// 246.202 us; speedup vs baseline: 1.2210x; 1.2210x over previous
//
#include <hip/hip_runtime.h>

#define U_ROWS 20000
#define I_COLS 10000
#define LDI    10001
#define B_N    4096
#define SC     625        // c-gemm K-steps (20000/32)
#define NPAN_C 79         // c-gemm i-panels of 128 (ceil(10000/128))
#define NC_C   8          // c-gemm K-split
#define SUT    79         // u-gemm k-tiles of 128 (ceil(10000/128))
#define NP_U   8          // u-gemm K-split
#define SPU_T  10         // ceil(SUT/NP_U)
#define SU_P   316        // packed 32-k-steps for u-gemm (79*4)

typedef __attribute__((ext_vector_type(8))) __bf16 bf16x8;
typedef __attribute__((ext_vector_type(4))) float f32x4;

__device__ __forceinline__ unsigned short f2bf(float f) {
    unsigned int u = __float_as_uint(f);
    return (unsigned short)((u + 0x7FFFu + ((u >> 16) & 1u)) >> 16);  // RTN-even
}

// Fused prep: pack W_u/W_i into MFMA B-fragment order (bf16), transpose MLP
// weights, transposed WuT/WiT for the coalesced epilogue gather.
// Pack layout: out[((s*4+nb)*64 + l)*8 + j] = bf16(W[nb*16+(l&15)][s*32+(l>>4)*8+j])
__global__ __launch_bounds__(256) void k_prep(
    const float* __restrict__ Wu, const float* __restrict__ Wi,
    unsigned short* __restrict__ Pu, unsigned short* __restrict__ Pi,
    const float* __restrict__ W1, const float* __restrict__ W2, const float* __restrict__ W3,
    float* __restrict__ Wt1, float* __restrict__ Wt2, float* __restrict__ Wt3,
    float* __restrict__ WuT, float* __restrict__ WiT)
{
    const int NU = SU_P * 2048, NC2 = SC * 2048;
    int idx = blockIdx.x * 256 + threadIdx.x;
    if (idx < NU + NC2) {
        const float* W = (idx < NU) ? Wu : Wi;
        unsigned short* out = (idx < NU) ? Pu : Pi;
        int n_k = (idx < NU) ? I_COLS : U_ROWS;
        int li = (idx < NU) ? idx : idx - NU;
        int j  = li & 7;
        int l  = (li >> 3) & 63;
        int nb = (li >> 9) & 3;
        int s  = li >> 11;
        int n  = nb * 16 + (l & 15);
        int k  = s * 32 + ((l >> 4) << 3) + j;
        float v = (k < n_k) ? W[(size_t)n * n_k + k] : 0.0f;
        out[li] = f2bf(v);
        return;
    }
    int r2 = idx - (NU + NC2);
    if (r2 < 64 * 128) { int r = r2 / 128, c = r2 % 128; Wt1[c * 64 + r] = W1[r2]; return; }
    r2 -= 64 * 128;
    if (r2 < 32 * 64)  { int r = r2 / 64,  c = r2 % 64;  Wt2[c * 32 + r] = W2[r2]; return; }
    r2 -= 32 * 64;
    if (r2 < 16 * 32)  { int r = r2 / 32,  c = r2 % 32;  Wt3[c * 16 + r] = W3[r2]; return; }
    r2 -= 16 * 32;
    if (r2 < 64 * I_COLS) {
        int n = r2 / I_COLS, k = r2 % I_COLS;
        WuT[(size_t)k * 64 + n] = Wu[r2];
        return;
    }
    r2 -= 64 * I_COLS;
    if (r2 < 64 * U_ROWS) {
        int n = r2 / U_ROWS, u = r2 % U_ROWS;
        WiT[(size_t)u * 64 + n] = Wi[r2];
        return;
    }
}

// Fused GEMM. Staging: lane-contiguous wave-instrs (2 rows x 512B each);
// A packed to bf16 at stage time (0/1 -> exact).
//  c-gemm: 2-DEEP register prefetch (avA/avB, load-to-use = 2 steps).
//  u-gemm: 1-deep.
__global__ __launch_bounds__(256) void k_gemm(
    const float* __restrict__ A, const int* __restrict__ uidx,
    const unsigned short* __restrict__ Bpu, const unsigned short* __restrict__ Bpc,
    float* __restrict__ Upart, float* __restrict__ Cpart,
    int spc)
{
    __shared__ char smem[64 * 256];     // 16 KB (u-path size; c uses 8 KB)
    const int t = threadIdx.x, lane = t & 63, w = t >> 6;
    const int rl = lane & 15, g = lane >> 4;
    const int half = lane >> 5, lc = lane & 31;
    const int CB = NPAN_C * NC_C;
    const char* Ab = (const char*)A;

    if ((int)blockIdx.x < CB) {
        // ---------------- c-gemm ----------------
        const int p = blockIdx.x % NC_C, mb = blockIdx.x / NC_C;
        const int i0 = mb * 128;
        const int s0 = p * spc;
        const int s1 = (SC < s0 + spc) ? SC : (s0 + spc);

        f32x4 acc[2][4];
#pragma unroll
        for (int mt = 0; mt < 2; ++mt)
#pragma unroll
            for (int nb = 0; nb < 4; ++nb) acc[mt][nb] = (f32x4)(0.0f);

        // staging: instr q (0..3): LDS k-row r = q*8 + w*2 + half, cols lc*4..+3
#define CROW(q) ((q) * 8 + w * 2 + half)
#define CLOADT(dst, S) do { \
        _Pragma("unroll") \
        for (int q_ = 0; q_ < 4; ++q_) { \
            size_t gr_ = (size_t)((S) * 32 + CROW(q_)) * LDI + i0 + lc * 4; \
            dst[q_] = *(const f32x4*)(Ab + gr_ * 4); \
        } } while (0)

#define CWRITE(src) do { \
        _Pragma("unroll") \
        for (int q_ = 0; q_ < 4; ++q_) { \
            int r_ = CROW(q_); \
            unsigned int lo_ = __builtin_amdgcn_perm(__float_as_uint(src[q_][1]), \
                                                     __float_as_uint(src[q_][0]), 0x07060302); \
            unsigned int hi_ = __builtin_amdgcn_perm(__float_as_uint(src[q_][3]), \
                                                     __float_as_uint(src[q_][2]), 0x07060302); \
            uint2 v2_; v2_.x = lo_; v2_.y = hi_; \
            *(uint2*)(smem + r_ * 256 + ((lc * 8) ^ (((r_ >> 3) & 3) << 5))) = v2_; \
        } } while (0)

#define CCOMPUTE(S) do { \
        bf16x8 bv_[4]; \
        _Pragma("unroll") \
        for (int nb_ = 0; nb_ < 4; ++nb_) \
            bv_[nb_] = *(const bf16x8*)(Bpc + ((size_t)((S) * 4 + nb_) * 64 + lane) * 8); \
        _Pragma("unroll") \
        for (int mt_ = 0; mt_ < 2; ++mt_) { \
            const char* rp_ = smem + (((w * 32 + mt_ * 16 + rl) * 2) ^ (g << 5)); \
            unsigned int pr_[4]; \
            _Pragma("unroll") \
            for (int q_ = 0; q_ < 4; ++q_) { \
                unsigned int e0_ = *(const unsigned short*)(rp_ + (g * 8 + 2 * q_) * 256); \
                unsigned int e1_ = *(const unsigned short*)(rp_ + (g * 8 + 2 * q_ + 1) * 256); \
                pr_[q_] = e0_ | (e1_ << 16); \
            } \
            union { unsigned int i[4]; bf16x8 v; } af_; \
            af_.i[0] = pr_[0]; af_.i[1] = pr_[1]; af_.i[2] = pr_[2]; af_.i[3] = pr_[3]; \
            _Pragma("unroll") \
            for (int nb_ = 0; nb_ < 4; ++nb_) \
                acc[mt_][nb_] = __builtin_amdgcn_mfma_f32_16x16x32_bf16(af_.v, bv_[nb_], acc[mt_][nb_], 0, 0, 0); \
        } } while (0)

        f32x4 avA[4], avB[4];
        CLOADT(avA, s0);
        if (s0 + 1 < s1) CLOADT(avB, s0 + 1);

        int s = s0;
        for (; s + 1 < s1; s += 2) {
            __syncthreads();
            CWRITE(avA);
            __syncthreads();
            if (s + 2 < s1) CLOADT(avA, s + 2);
            CCOMPUTE(s);
            __syncthreads();
            CWRITE(avB);
            __syncthreads();
            if (s + 3 < s1) CLOADT(avB, s + 3);
            CCOMPUTE(s + 1);
        }
        if (s < s1) {
            __syncthreads();
            CWRITE(avA);
            __syncthreads();
            CCOMPUTE(s);
        }

        float* outp = Cpart + (size_t)p * I_COLS * 64;
#pragma unroll
        for (int mt = 0; mt < 2; ++mt)
#pragma unroll
            for (int nb = 0; nb < 4; ++nb)
#pragma unroll
                for (int reg = 0; reg < 4; ++reg) {
                    int i = i0 + w * 32 + mt * 16 + g * 4 + reg;
                    if (i < I_COLS) outp[(size_t)i * 64 + nb * 16 + rl] = acc[mt][nb][reg];
                }
    } else {
        // ---------------- u-gemm (1-deep) ----------------
        const int bid = blockIdx.x - CB;
        const int p = bid % NP_U, mb = bid / NP_U;
        const int r0 = mb * 64;
        const int s0 = p * SPU_T;
        const int s1 = (SUT < s0 + SPU_T) ? SUT : (s0 + SPU_T);

        int ur[8];
#pragma unroll
        for (int q = 0; q < 8; ++q) ur[q] = uidx[r0 + (q * 4 + w) * 2 + half];

        f32x4 acc[4];
#pragma unroll
        for (int nb = 0; nb < 4; ++nb) acc[nb] = (f32x4)(0.0f);

#define ULOADT(dst, S) do { \
        _Pragma("unroll") \
        for (int q_ = 0; q_ < 8; ++q_) { \
            size_t ad_ = (size_t)ur[q_] * LDI + (S) * 128 + lc * 4; \
            dst[q_] = *(const f32x4*)(Ab + ad_ * 4); \
        } } while (0)

        f32x4 av[8];
        ULOADT(av, s0);
        for (int s = s0; s < s1; ++s) {
            __syncthreads();
#pragma unroll
            for (int q = 0; q < 8; ++q) {
                int r = (q * 4 + w) * 2 + half;
                unsigned int lo = __builtin_amdgcn_perm(__float_as_uint(av[q][1]),
                                                        __float_as_uint(av[q][0]), 0x07060302);
                unsigned int hi = __builtin_amdgcn_perm(__float_as_uint(av[q][3]),
                                                        __float_as_uint(av[q][2]), 0x07060302);
                uint2 v2; v2.x = lo; v2.y = hi;
                *(uint2*)(smem + r * 256 + ((lc * 8) ^ ((r & 7) << 4))) = v2;
            }
            __syncthreads();
            if (s + 1 < s1) ULOADT(av, s + 1);

            const int r_loc = w * 16 + rl;
            const char* rp = smem + r_loc * 256;
            const int rm = (r_loc & 7) << 4;
#pragma unroll
            for (int ks = 0; ks < 4; ++ks) {
                const int kk = s * 4 + ks;
                bf16x8 afv = *(const bf16x8*)(rp + ((ks * 64 + g * 16) ^ rm));
                bf16x8 bv[4];
#pragma unroll
                for (int nb = 0; nb < 4; ++nb)
                    bv[nb] = *(const bf16x8*)(Bpu + ((size_t)(kk * 4 + nb) * 64 + lane) * 8);
#pragma unroll
                for (int nb = 0; nb < 4; ++nb)
                    acc[nb] = __builtin_amdgcn_mfma_f32_16x16x32_bf16(afv, bv[nb], acc[nb], 0, 0, 0);
            }
        }

        float* outp = Upart + (size_t)p * B_N * 64;
#pragma unroll
        for (int nb = 0; nb < 4; ++nb)
#pragma unroll
            for (int reg = 0; reg < 4; ++reg) {
                int r = r0 + w * 16 + g * 4 + reg;
                outp[(size_t)r * 64 + nb * 16 + rl] = acc[nb][reg];
            }
    }
}

__device__ __forceinline__ float redsum64(float x) {
    x += __shfl_xor(x, 1);  x += __shfl_xor(x, 2);  x += __shfl_xor(x, 4);
    x += __shfl_xor(x, 8);  x += __shfl_xor(x, 16); x += __shfl_xor(x, 32);
    return x;
}
__device__ __forceinline__ float redsum32(float x) {
    x += __shfl_xor(x, 1); x += __shfl_xor(x, 2); x += __shfl_xor(x, 4);
    x += __shfl_xor(x, 8); x += __shfl_xor(x, 16);
    return x;
}
__device__ __forceinline__ float redsum16(float x) {
    x += __shfl_xor(x, 1); x += __shfl_xor(x, 2); x += __shfl_xor(x, 4);
    x += __shfl_xor(x, 8);
    return x;
}

// one wave per batch row: reduce partials, mask corrections, full MLP
__global__ __launch_bounds__(256) void k_epi(
    const float* __restrict__ A, const int* __restrict__ uidx, const int* __restrict__ iidx,
    const float* __restrict__ Upart, const float* __restrict__ Cpart, int NP, int NC,
    const float* __restrict__ WuT, const float* __restrict__ WiT,
    const float* __restrict__ Wt1, const float* __restrict__ b1, const float* __restrict__ g1, const float* __restrict__ be1,
    const float* __restrict__ Wt2, const float* __restrict__ b2, const float* __restrict__ g2, const float* __restrict__ be2,
    const float* __restrict__ Wt3, const float* __restrict__ b3, const float* __restrict__ g3, const float* __restrict__ be3,
    const float* __restrict__ Wp, const float* __restrict__ bp,
    float* __restrict__ out)
{
    const int t = threadIdx.x, lane = t & 63, w = t >> 6;
    const int r = blockIdx.x * 4 + w;
    const int u = uidx[r], it = iidx[r];
    const float a_ui = A[(size_t)u * LDI + it];

    float ue = 0.f, ie = 0.f;
    for (int p0 = 0; p0 < NP; ++p0) ue += Upart[((size_t)p0 * B_N + r) * 64 + lane];
    for (int p0 = 0; p0 < NC; ++p0) ie += Cpart[((size_t)p0 * I_COLS + it) * 64 + lane];
    ue -= a_ui * WuT[(size_t)it * 64 + lane];
    ie -= a_ui * WiT[(size_t)u * 64 + lane];

    // layer 1: 128 -> 64, LN, ReLU
    float h = b1[lane];
    for (int c = 0; c < 64; ++c) h += __shfl(ue, c) * Wt1[c * 64 + lane];
    for (int c = 0; c < 64; ++c) h += __shfl(ie, c) * Wt1[(64 + c) * 64 + lane];
    {
        float m = redsum64(h) * (1.0f / 64.0f);
        float d = h - m;
        float v = redsum64(d * d) * (1.0f / 64.0f);
        h = d * rsqrtf(v + 1e-5f) * g1[lane] + be1[lane];
        h = fmaxf(h, 0.0f);
    }
    // layer 2: 64 -> 32
    const int l2 = lane & 31;
    float h2 = b2[l2];
    for (int c = 0; c < 64; ++c) h2 += __shfl(h, c) * Wt2[c * 32 + l2];
    {
        float m = redsum32(h2) * (1.0f / 32.0f);
        float d = h2 - m;
        float v = redsum32(d * d) * (1.0f / 32.0f);
        h2 = d * rsqrtf(v + 1e-5f) * g2[l2] + be2[l2];
        h2 = fmaxf(h2, 0.0f);
    }
    // layer 3: 32 -> 16
    const int l3 = lane & 15;
    float h3 = b3[l3];
    for (int c = 0; c < 32; ++c) h3 += __shfl(h2, c) * Wt3[c * 16 + l3];
    {
        float m = redsum16(h3) * (1.0f / 16.0f);
        float d = h3 - m;
        float v = redsum16(d * d) * (1.0f / 16.0f);
        h3 = d * rsqrtf(v + 1e-5f) * g3[l3] + be3[l3];
        h3 = fmaxf(h3, 0.0f);
    }
    float tt = h3 * Wp[l3];
    tt = redsum16(tt);
    if (lane == 0) out[r] = tt + bp[0];
}

extern "C" void kernel_launch(void* const* d_in, const int* in_sizes, int n_in,
                              void* d_out, int out_size, void* d_ws, size_t ws_size,
                              hipStream_t stream)
{
    const float* A    = (const float*)d_in[0];
    const int*   uidx = (const int*)d_in[1];
    const int*   iidx = (const int*)d_in[2];
    const float* W_u  = (const float*)d_in[3];
    const float* W_i  = (const float*)d_in[4];
    const float* W1   = (const float*)d_in[5];
    const float* b1   = (const float*)d_in[6];
    const float* g1   = (const float*)d_in[7];
    const float* be1  = (const float*)d_in[8];
    const float* W2   = (const float*)d_in[9];
    const float* b2   = (const float*)d_in[10];
    const float* g2   = (const float*)d_in[11];
    const float* be2  = (const float*)d_in[12];
    const float* W3   = (const float*)d_in[13];
    const float* b3   = (const float*)d_in[14];
    const float* g3   = (const float*)d_in[15];
    const float* be3  = (const float*)d_in[16];
    const float* Wp   = (const float*)d_in[17];
    const float* bp   = (const float*)d_in[18];
    float* out = (float*)d_out;

    unsigned short* Wtu_p = (unsigned short*)d_ws;          // SU_P*2048 bf16
    unsigned short* Wti_p = Wtu_p + (size_t)SU_P * 2048;    // SC*2048 bf16
    float* Wt1 = (float*)(Wti_p + (size_t)SC * 2048);       // 128*64
    float* Wt2 = Wt1 + 128 * 64;
    float* Wt3 = Wt2 + 64 * 32;
    float* WuT = Wt3 + 32 * 16;                             // I_COLS*64
    float* WiT = WuT + (size_t)I_COLS * 64;                 // U_ROWS*64
    float* Upart = WiT + (size_t)U_ROWS * 64;               // NP_U*B_N*64
    float* Cpart = Upart + (size_t)NP_U * B_N * 64;         // NC_C*I_COLS*64

    int spc = (SC + NC_C - 1) / NC_C;

    int prep_tot = (SU_P + SC) * 2048 + 64 * 128 + 32 * 64 + 16 * 32
                 + 64 * I_COLS + 64 * U_ROWS;
    hipLaunchKernelGGL(k_prep, dim3((prep_tot + 255) / 256), dim3(256), 0, stream,
                       W_u, W_i, Wtu_p, Wti_p, W1, W2, W3, Wt1, Wt2, Wt3, WuT, WiT);

    hipLaunchKernelGGL(k_gemm, dim3(NPAN_C * NC_C + 64 * NP_U), dim3(256), 0, stream,
                       A, uidx, Wtu_p, Wti_p, Upart, Cpart, spc);

    hipLaunchKernelGGL(k_epi, dim3(B_N / 4), dim3(256), 0, stream,
                       A, uidx, iidx, Upart, Cpart, NP_U, NC_C,
                       WuT, WiT, Wt1, b1, g1, be1, Wt2, b2, g2, be2,
                       Wt3, b3, g3, be3, Wp, bp, out);
}